// Round 14
// baseline (168.471 us; speedup 1.0000x reference)
//
#include <hip/hip_runtime.h>

#define N_PTS 1000000
#define H_DIM 200
#define W_DIM 70400
#define FILL_V -9999999.0f
#define NXCD 8

// ws layout: counts8[8][W] int | wpack[6656 bf16] | feat[1M u32] | list4[8][W][slots] u32
#define COUNTS8_BYTES ((size_t)NXCD * W_DIM * sizeof(int))
#define WPACK_ELEMS  6656
#define WPACK_BYTES  ((size_t)WPACK_ELEMS * 2)
#define FEAT_BYTES   ((size_t)N_PTS * 4)

typedef __attribute__((ext_vector_type(4))) float f32x4;
typedef __attribute__((ext_vector_type(8))) short bf16x8;

__device__ __forceinline__ unsigned bperm_u(unsigned src_lane, unsigned v) {
    return (unsigned)__builtin_amdgcn_ds_bpermute((int)(src_lane << 2), (int)v);
}
__device__ __forceinline__ unsigned cvt_pk_bf16(float lo, float hi) {
    unsigned d;
    asm("v_cvt_pk_bf16_f32 %0, %1, %2" : "=v"(d) : "v"(lo), "v"(hi));
    return d;
}
__device__ __forceinline__ bf16x8 mk_frag(unsigned d0, unsigned d1,
                                          unsigned d2, unsigned d3) {
    union { unsigned u[4]; bf16x8 s; } u;
    u.u[0] = d0; u.u[1] = d1; u.u[2] = d2; u.u[3] = d3;
    return u.s;
}
// Which chiplet is this wave on? (m09-verified). Correctness does NOT depend
// on the value -- any 0..7 picks a partition; dedup merges all 8 partitions.
__device__ __forceinline__ unsigned xcc_id() {
    unsigned x;
    asm volatile("s_getreg_b32 %0, hwreg(HW_REG_XCC_ID)" : "=s"(x));
    return x & 7u;
}

// ---------------------------------------------------------------------------
// Prep (unchanged from R11, verified): A2 kappa'd, A1/A3/A4 linear.
// ---------------------------------------------------------------------------
__global__ void __launch_bounds__(256) pack_weights_kernel(
    const float* __restrict__ w1, const float* __restrict__ b1,
    const float* __restrict__ w2, const float* __restrict__ b2,
    const float* __restrict__ w3, const float* __restrict__ b3,
    const float* __restrict__ w4, const float* __restrict__ b4,
    unsigned short* __restrict__ wp)
{
    for (int idx = threadIdx.x; idx < WPACK_ELEMS; idx += 256) {
        const int rem  = idx & 511;
        const int lane = rem >> 3, j = rem & 7;
        const int c16 = lane & 15, gk = lane >> 4;
        const int kloc = gk * 8 + j;
        float v = 0.0f;
        if (idx < 1024) {                       // A1: linear
            const int row = (idx >> 9) * 16 + c16, k = kloc;
            if (row < 18) v = (k < 4) ? w1[row * 4 + k] : (k == 4 ? b1[row] : 0.0f);
        } else if (idx < 2560) {                // A2: KAPPA (R11-verified)
            const int row = ((idx - 1024) >> 9) * 16 + c16;
            const int f = (j < 4) ? (4 * gk + j) : (16 + 4 * gk + (j - 4));
            if (row < 36) v = (f < 18) ? w2[row * 18 + f] : (f == 18 ? b2[row] : 0.0f);
        } else if (idx < 5632) {                // A3: linear
            const int f = (idx - 2560) >> 9;
            const int row = (f >> 1) * 16 + c16, k = (f & 1) * 32 + kloc;
            if (row < 36) v = (k < 36) ? w3[row * 36 + k] : (k == 36 ? b3[row] : 0.0f);
        } else {                                // A4: linear
            const int row = c16, k = ((idx - 5632) >> 9) * 32 + kloc;
            if (row == 0) v = (k < 36) ? w4[k] : (k == 36 ? b4[0] : 0.0f);
        }
        const unsigned b = __float_as_uint(v);  // f32 -> bf16 RNE
        wp[idx] = (unsigned short)((b + 0x7FFFu + ((b >> 16) & 1u)) >> 16);
    }
}

// ---------------------------------------------------------------------------
// Kernel A v11 (R14): R13 body (verified) + XCD-PARTITIONED scatter.
// R13 post-mortem: 4B keys left WRITE_SIZE (~64MB) and dur (62us) unchanged
// -> writeback is governed by dirty (line,XCD) PAIRS: each column's list
// line collects entries from ~6-7 different XCDs; each non-coherent L2
// writes back its own partial copy -> ~1M pairs x 64B ~= 60MB at ~1 TB/s =
// the 62us wall. Fix: per-XCD counts + per-XCD list chunk per column ->
// each list line is dirtied by exactly ONE XCD. Chunk occupancy
// Poisson(14.2/8=1.78); slots>=12 -> overflow P ~1e-8/chunk (0 expected).
// ---------------------------------------------------------------------------
__global__ void __launch_bounds__(256) mlp_scatter_kernel(
    const float* __restrict__ input,        // [4][N]
    const int* __restrict__ tindex,         // [N][2] int32 (row, col)
    const unsigned short* __restrict__ wp,  // packed bf16 fragments
    int* __restrict__ counts8,              // [8][W]
    unsigned* __restrict__ feat,            // [N] value bits, linear
    unsigned* __restrict__ list4,           // [8][W][slots] keys
    int slots)
{
    if (tindex[0] == -1) return;            // empty-branch

    const int l   = threadIdx.x & 63;
    const int wav = (blockIdx.x * 256 + threadIdx.x) >> 6;
    const int base = wav << 6;
    if (base >= N_PTS) return;              // whole-wave early out (N%64==0)
    const int i = base + l;
    const int c16 = l & 15, g = l >> 4;

    const unsigned xcd = xcc_id();          // wave-uniform partition id

    // scatter-slot atomic first; latency hides under the GEMMs
    const int2 hw = ((const int2*)tindex)[i];
    const size_t cell = (size_t)xcd * W_DIM + (size_t)hw.y;
    const int pos = atomicAdd(&counts8[cell], 1);

    const bf16x8* __restrict__ wf = (const bf16x8*)wp;
    const bf16x8 A1_0 = wf[0 * 64 + l], A1_1 = wf[1 * 64 + l];
    const bf16x8 A2_0 = wf[2 * 64 + l], A2_1 = wf[3 * 64 + l], A2_2 = wf[4 * 64 + l];
    const bf16x8 A3_00 = wf[5 * 64 + l], A3_01 = wf[6 * 64 + l];
    const bf16x8 A3_10 = wf[7 * 64 + l], A3_11 = wf[8 * 64 + l];
    const bf16x8 A3_20 = wf[9 * 64 + l], A3_21 = wf[10 * 64 + l];
    const bf16x8 A4_0 = wf[11 * 64 + l], A4_1 = wf[12 * 64 + l];

    const f32x4 zf = {0.0f, 0.0f, 0.0f, 0.0f};

    const float x0 = input[0 * N_PTS + i], x1 = input[1 * N_PTS + i];
    const float x2 = input[2 * N_PTS + i], x3 = input[3 * N_PTS + i];
    const unsigned xp01 = cvt_pk_bf16(x0, x1);
    const unsigned xp23 = cvt_pk_bf16(x2, x3);

    // ---- L1 ---- (R11 exact)
    unsigned P1[4][2][2];
#pragma unroll
    for (int t = 0; t < 4; ++t) {
        const unsigned srcl = (unsigned)(16 * t + c16);
        const unsigned bx0 = bperm_u(srcl, xp01);
        const unsigned bx1 = bperm_u(srcl, xp23);
        const bf16x8 B = mk_frag((g == 0) ? bx0 : 0u,
                                 (g == 0) ? bx1 : 0u,
                                 (g == 0) ? 0x3F80u : 0u, 0u);
        const f32x4 D0 = __builtin_amdgcn_mfma_f32_16x16x32_bf16(A1_0, B, zf, 0, 0, 0);
        const f32x4 D1 = __builtin_amdgcn_mfma_f32_16x16x32_bf16(A1_1, B, zf, 0, 0, 0);
        P1[t][0][0] = cvt_pk_bf16(fmaxf(D0.x, 0.f), fmaxf(D0.y, 0.f));
        P1[t][0][1] = cvt_pk_bf16(fmaxf(D0.z, 0.f), fmaxf(D0.w, 0.f));
        P1[t][1][0] = cvt_pk_bf16(fmaxf(D1.x, 0.f), fmaxf(D1.y, 0.f));
        P1[t][1][1] = cvt_pk_bf16(fmaxf(D1.z, 0.f), fmaxf(D1.w, 0.f));
    }

    // ---- L2: kappa self-pack ---- (R11 exact)
    unsigned P2[4][3][2];
#pragma unroll
    for (int t = 0; t < 4; ++t) {
        const bf16x8 B = mk_frag(P1[t][0][0], P1[t][0][1], P1[t][1][0],
                                 (g == 0) ? 0x3F80u : P1[t][1][1]);
        const f32x4 D0 = __builtin_amdgcn_mfma_f32_16x16x32_bf16(A2_0, B, zf, 0, 0, 0);
        const f32x4 D1 = __builtin_amdgcn_mfma_f32_16x16x32_bf16(A2_1, B, zf, 0, 0, 0);
        const f32x4 D2 = __builtin_amdgcn_mfma_f32_16x16x32_bf16(A2_2, B, zf, 0, 0, 0);
        P2[t][0][0] = cvt_pk_bf16(fmaxf(D0.x, 0.f), fmaxf(D0.y, 0.f));
        P2[t][0][1] = cvt_pk_bf16(fmaxf(D0.z, 0.f), fmaxf(D0.w, 0.f));
        P2[t][1][0] = cvt_pk_bf16(fmaxf(D1.x, 0.f), fmaxf(D1.y, 0.f));
        P2[t][1][1] = cvt_pk_bf16(fmaxf(D1.z, 0.f), fmaxf(D1.w, 0.f));
        P2[t][2][0] = cvt_pk_bf16(fmaxf(D2.x, 0.f), fmaxf(D2.y, 0.f));
        P2[t][2][1] = cvt_pk_bf16(fmaxf(D2.z, 0.f), fmaxf(D2.w, 0.f));
    }

    // ---- L3 ---- (R9-exact bperm gather)
    unsigned P3[4][3][2];
#pragma unroll
    for (int t = 0; t < 4; ++t) {
        unsigned dk0[4], dk1[4];
#pragma unroll
        for (int p = 0; p < 4; ++p) {
            const int Rl = (4 * g + p) & 7;
            const unsigned srcl = (unsigned)(c16 + 16 * (Rl >> 1));
            const unsigned lo = bperm_u(srcl, P2[t][0][p & 1]);
            const unsigned hi = bperm_u(srcl, P2[t][1][p & 1]);
            const unsigned m2 = bperm_u(srcl, P2[t][2][p & 1]);
            dk0[p] = (4 * g + p < 8) ? lo : hi;
            dk1[p] = (4 * g + p < 8) ? m2 : 0u;
        }
        if (g == 0) dk1[2] = (dk1[2] & 0xFFFF0000u) | 0x3F80u;
        const bf16x8 B0 = mk_frag(dk0[0], dk0[1], dk0[2], dk0[3]);
        const bf16x8 B1 = mk_frag(dk1[0], dk1[1], dk1[2], dk1[3]);
        f32x4 D0 = __builtin_amdgcn_mfma_f32_16x16x32_bf16(A3_00, B0, zf, 0, 0, 0);
        D0 = __builtin_amdgcn_mfma_f32_16x16x32_bf16(A3_01, B1, D0, 0, 0, 0);
        f32x4 D1 = __builtin_amdgcn_mfma_f32_16x16x32_bf16(A3_10, B0, zf, 0, 0, 0);
        D1 = __builtin_amdgcn_mfma_f32_16x16x32_bf16(A3_11, B1, D1, 0, 0, 0);
        f32x4 D2 = __builtin_amdgcn_mfma_f32_16x16x32_bf16(A3_20, B0, zf, 0, 0, 0);
        D2 = __builtin_amdgcn_mfma_f32_16x16x32_bf16(A3_21, B1, D2, 0, 0, 0);
        P3[t][0][0] = cvt_pk_bf16(fmaxf(D0.x, 0.f), fmaxf(D0.y, 0.f));
        P3[t][0][1] = cvt_pk_bf16(fmaxf(D0.z, 0.f), fmaxf(D0.w, 0.f));
        P3[t][1][0] = cvt_pk_bf16(fmaxf(D1.x, 0.f), fmaxf(D1.y, 0.f));
        P3[t][1][1] = cvt_pk_bf16(fmaxf(D1.z, 0.f), fmaxf(D1.w, 0.f));
        P3[t][2][0] = cvt_pk_bf16(fmaxf(D2.x, 0.f), fmaxf(D2.y, 0.f));
        P3[t][2][1] = cvt_pk_bf16(fmaxf(D2.z, 0.f), fmaxf(D2.w, 0.f));
    }

    // ---- L4 ---- (R9-exact)
    float vout[4];
#pragma unroll
    for (int t = 0; t < 4; ++t) {
        unsigned dk0[4], dk1[4];
#pragma unroll
        for (int p = 0; p < 4; ++p) {
            const int Rl = (4 * g + p) & 7;
            const unsigned srcl = (unsigned)(c16 + 16 * (Rl >> 1));
            const unsigned lo = bperm_u(srcl, P3[t][0][p & 1]);
            const unsigned hi = bperm_u(srcl, P3[t][1][p & 1]);
            const unsigned m2 = bperm_u(srcl, P3[t][2][p & 1]);
            dk0[p] = (4 * g + p < 8) ? lo : hi;
            dk1[p] = (4 * g + p < 8) ? m2 : 0u;
        }
        if (g == 0) dk1[2] = (dk1[2] & 0xFFFF0000u) | 0x3F80u;
        const bf16x8 B0 = mk_frag(dk0[0], dk0[1], dk0[2], dk0[3]);
        const bf16x8 B1 = mk_frag(dk1[0], dk1[1], dk1[2], dk1[3]);
        f32x4 D = __builtin_amdgcn_mfma_f32_16x16x32_bf16(A4_0, B0, zf, 0, 0, 0);
        D = __builtin_amdgcn_mfma_f32_16x16x32_bf16(A4_1, B1, D, 0, 0, 0);
        vout[t] = D.x;
    }

    // redistribute: point p's value sits in lane (p&15) of tile (p>>4)
    const unsigned r0 = bperm_u((unsigned)c16, __float_as_uint(vout[0]));
    const unsigned r1 = bperm_u((unsigned)c16, __float_as_uint(vout[1]));
    const unsigned r2 = bperm_u((unsigned)c16, __float_as_uint(vout[2]));
    const unsigned r3 = bperm_u((unsigned)c16, __float_as_uint(vout[3]));
    const unsigned vr = (g < 2) ? ((g == 0) ? r0 : r1) : ((g == 2) ? r2 : r3);

    feat[i] = vr;                           // linear coalesced value stream
    if (pos < slots)                        // per-XCD chunk: one line, one XCD
        list4[cell * (size_t)slots + pos] = ((unsigned)i << 8) | (unsigned)hw.x;
}

// Wave-local LDS ordering (colmax): drain this wave's DS ops.
__device__ __forceinline__ void lds_wave_fence() {
    asm volatile("s_waitcnt lgkmcnt(0)" ::: "memory");
}

// ---------------------------------------------------------------------------
// Kernel B v5 (R14): same verified key-max dedup table, now merging 8
// per-XCD chunks per column. Lane l covers chunk x=l>>3: entry A at slot
// l&7, entry B at slot (l&7)+8 (covers up to 16 slots/chunk; slots<=16).
// Winner values gathered from feat[key>>8] before the fence (latency hidden).
// ---------------------------------------------------------------------------
__global__ void __launch_bounds__(256) colmax_kernel(
    const int* __restrict__ tindex,
    const int* __restrict__ counts8,
    const unsigned* __restrict__ list4,
    const unsigned* __restrict__ feat,
    float* __restrict__ out,
    int slots)
{
    __shared__ unsigned rowwin[4][200];
    const int lane = threadIdx.x;        // 0..63
    const int y    = threadIdx.y;        // 0..3
    unsigned* tbl = rowwin[y];

    const bool empty = (tindex[0] == -1);

    if (blockIdx.x == 0 && lane == 0 && y == 0)
        out[W_DIM] = empty ? 0.0f : 1.0f;    // flag output

    tbl[lane]       = 0u;
    tbl[lane + 64]  = 0u;
    tbl[lane + 128] = 0u;
    if (lane < 8) tbl[lane + 192] = 0u;
    lds_wave_fence();

    const int x   = lane >> 3;           // xcd chunk 0..7
    const int sub = lane & 7;            // slot within chunk (+8 for entry B)

    const int step = gridDim.x * 4;
    for (int w = blockIdx.x * 4 + y; w < W_DIM; w += step) {
        int c = 0;
        if (!empty) {
            c = counts8[(size_t)x * W_DIM + w];
            if (c > slots) c = slots;
        }

        const size_t basew = ((size_t)x * W_DIM + w) * (size_t)slots;
        unsigned eA = 0u, eB = 0u, fA = 0u, fB = 0u;
        const bool hA = (sub < c);
        const bool hB = (sub + 8 < c);
        if (hA) {
            eA = list4[basew + sub];
            fA = feat[eA >> 8];
            atomicMax(&tbl[eA & 0xFFu], eA);
        }
        if (hB) {
            eB = list4[basew + sub + 8];
            fB = feat[eB >> 8];
            atomicMax(&tbl[eB & 0xFFu], eB);
        }
        lds_wave_fence();                 // all keys final

        float v = FILL_V;
        unsigned winA = 0u, winB = 0u;
        if (hA) winA = tbl[eA & 0xFFu];   // reads BEFORE any zero-write
        if (hB) winB = tbl[eB & 0xFFu];
        if (hA && winA == eA) v = __uint_as_float(fA);
        if (hB && winB == eB) v = fmaxf(v, __uint_as_float(fB));
        if (hA) tbl[eA & 0xFFu] = 0u;     // restore zero-table invariant
        if (hB) tbl[eB & 0xFFu] = 0u;
        lds_wave_fence();                 // zeros land before next column

#pragma unroll
        for (int off = 32; off > 0; off >>= 1)
            v = fmaxf(v, __shfl_down(v, off, 64));

        if (lane == 0) out[w] = v;
    }
}

extern "C" void kernel_launch(void* const* d_in, const int* in_sizes, int n_in,
                              void* d_out, int out_size, void* d_ws, size_t ws_size,
                              hipStream_t stream) {
    const float* input  = (const float*)d_in[0];
    const int*   tindex = (const int*)d_in[1];   // int32 on device
    const float* w1 = (const float*)d_in[2];
    const float* b1 = (const float*)d_in[3];
    const float* w2 = (const float*)d_in[4];
    const float* b2 = (const float*)d_in[5];
    const float* w3 = (const float*)d_in[6];
    const float* b3 = (const float*)d_in[7];
    const float* w4 = (const float*)d_in[8];
    const float* b4 = (const float*)d_in[9];
    float* out = (float*)d_out;

    int*            counts8 = (int*)d_ws;
    unsigned short* wpack   = (unsigned short*)((char*)d_ws + COUNTS8_BYTES);
    unsigned*       feat    = (unsigned*)((char*)d_ws + COUNTS8_BYTES + WPACK_BYTES);
    unsigned*       list4   = (unsigned*)((char*)d_ws + COUNTS8_BYTES + WPACK_BYTES + FEAT_BYTES);

    size_t head = COUNTS8_BYTES + WPACK_BYTES + FEAT_BYTES;
    size_t avail = (ws_size > head) ? ws_size - head : 0;
    // per-slot cost across all partitions: 8 * W * 4B
    int slots = (int)(avail / ((size_t)NXCD * W_DIM * sizeof(unsigned)));
    if (slots > 16) slots = 16;   // colmax covers <=16 slots/chunk
    if (slots < 1)  slots = 1;    // evidence (R0-R13): ws >= 36MB -> slots >= 13

    (void)hipMemsetAsync(counts8, 0, COUNTS8_BYTES, stream);

    pack_weights_kernel<<<1, 256, 0, stream>>>(w1, b1, w2, b2, w3, b3, w4, b4, wpack);

    mlp_scatter_kernel<<<(N_PTS / 64 + 3) / 4, 256, 0, stream>>>(
        input, tindex, wpack, counts8, feat, list4, slots);

    colmax_kernel<<<2200, dim3(64, 4), 0, stream>>>(
        tindex, counts8, list4, feat, out, slots);
}